// Round 12
// baseline (278.606 us; speedup 1.0000x reference)
//
#include <hip/hip_runtime.h>
#include <cmath>

namespace {

typedef _Float16 half8 __attribute__((ext_vector_type(8)));
typedef float f32x4 __attribute__((ext_vector_type(4)));

constexpr int kTokens = 16384;
constexpr int kD      = 7168;
constexpr int kE      = 256;
constexpr int kTopK   = 8;
constexpr float kRouteScale = 2.5f;

constexpr int BM     = 32;
constexpr int BK     = 32;               // MFMA k-tile
constexpr int KSTEP  = 128;              // k per barrier step (4 tiles)
constexpr int NT     = kD / BK;          // 224 k-tiles
constexpr int NSTEP  = kD / KSTEP;       // 56 steps
constexpr float kS  = 4096.0f;           // limb scale 2^12
constexpr float kC  = 0.000244140625f;   // 2^-12 (exact)
constexpr size_t kWsTileB = 32768;       // per-ktile W image: limb0 16K + limb1 16K
constexpr size_t kWsNeed  = (size_t)NT * kWsTileB;   // 7,340,032 B

// Convoy barrier WITHOUT the __syncthreads vmcnt(0) drain: only LDS ops must
// retire for cross-wave visibility (vmem results are per-lane registers).
__device__ inline void convoy_barrier() {
    asm volatile("s_waitcnt lgkmcnt(0)" ::: "memory");
    __builtin_amdgcn_s_barrier();
    asm volatile("" ::: "memory");
}

// ---------------------------------------------------------------------------
// Pre-pass: W [256][7168] f32 -> per-ktile B-fragment images, 2 scaled f16
// limbs.  Slot for expert e, k-group kg (8 k's): (e>>4)*64 + kg*16 + (e&15).
// Lane l of a wave reading colfrag f at f*1024 + l*16 gets its MFMA B frag.
// (unchanged since r3; validated absmax 0)
// ---------------------------------------------------------------------------
__global__ void wconv_kernel(const float* __restrict__ W, unsigned char* __restrict__ ws)
{
    const int e = blockIdx.x;
    const int t = threadIdx.x;            // 0..895
    const float* src = W + (size_t)e * kD + (size_t)t * 8;
    float v[8];
    *reinterpret_cast<float4*>(v)     = *reinterpret_cast<const float4*>(src);
    *reinterpret_cast<float4*>(v + 4) = *reinterpret_cast<const float4*>(src + 4);
    half8 h, l;
#pragma unroll
    for (int j = 0; j < 8; ++j) {
        _Float16 hh = (_Float16)v[j];
        h[j] = hh;
        l[j] = (_Float16)((v[j] - (float)hh) * kS);
    }
    const int kt = t >> 2;
    const int kg = t & 3;
    const size_t off = (size_t)kt * kWsTileB +
                       (size_t)(((e >> 4) << 6) + (kg << 4) + (e & 15)) * 16;
    *reinterpret_cast<half8*>(ws + off)         = h;
    *reinterpret_cast<half8*>(ws + off + 16384) = l;
}

// ---------------------------------------------------------------------------
// Main fused kernel, round 12 = round 10 base with TWO changes:
//  (1) wl double-buffered like wh (bl[parity][colfrag], loaded one sub-tile
//      ahead) — kills the per-sub-tile JIT vmcnt stall before the last 4
//      MFMAs (r7/r10 loaded wl at the top of the consuming sub-tile).
//  (2) sub-tile rotation kk0 = wid&3 — waves within a block start the step
//      at different k-sub-tiles, so one wave's ds_read burst overlaps
//      another wave's MFMA cluster instead of phase-aligned bursts.
// 512 threads = 8 waves; block tile 32x256; wave tile 32x32; grid 512 =
// 2 blocks/CU.  A: LDS dbuf 2x16KB swizzled limbs, KSTEP=128.  B: direct
// global->reg from pre-baked fragment images, parity reg-dbuf (wh AND wl).
// 3 products, acc0 spilled into accL every 8 steps (validated r7/r10).
// ---------------------------------------------------------------------------
__global__ __launch_bounds__(512, 4)
void gate_mfma(const float* __restrict__ x,
               const unsigned char* __restrict__ wst,
               const float* __restrict__ bias,
               float* __restrict__ out)
{
    __shared__ unsigned char lds[32896];

    const int t    = threadIdx.x;
    const int lane = t & 63;
    const int wid  = t >> 6;             // 0..7 -> 32-col group
    const int kk0  = wid & 3;            // per-wave sub-tile rotation
    const int m0   = blockIdx.x * BM;
    const int l15  = lane & 15;
    const int lg   = lane >> 4;

    // --- A staging map: thread t stages 8 consecutive k's of one row.
    const int srow = t >> 4;             // 0..31
    const int skc  = t & 15;             // k chunk: k = skc*8 .. +7 (within step)
    const unsigned waddr = (unsigned)(((skc >> 2) << 12) + ((srow >> 4) << 10) +
                                      ((skc & 3) << 8) + ((((srow & 15) ^ skc) & 15) << 4));
    const float* xsrc = x + (size_t)(m0 + srow) * kD + (size_t)(skc * 8);

    // --- B: lane's fragment pointer (colfrags wid*2, wid*2+1)
    const unsigned char* wb = wst + (size_t)(wid * 2) * 1024 + (size_t)lane * 16;

    f32x4 acc0[2][2], acc1[2][2], accL[2][2];
#pragma unroll
    for (int i = 0; i < 2; ++i)
#pragma unroll
        for (int j = 0; j < 2; ++j) {
            acc0[i][j] = f32x4{0.f,0.f,0.f,0.f};
            acc1[i][j] = f32x4{0.f,0.f,0.f,0.f};
            accL[i][j] = f32x4{0.f,0.f,0.f,0.f};
        }

    half8 bh[2][2];      // [parity][colfrag]  W limb0, 1 sub-tile ahead
    half8 bl[2][2];      // [parity][colfrag]  W limb1, 1 sub-tile ahead
    half8 axh[2][2];     // [parity][rowfrag]  A limb0
    half8 axm[2][2];     // [parity][rowfrag]  A limb1

    auto LOADB = [&](int pp, int kt) {
        const unsigned char* p = wb + (size_t)kt * kWsTileB;
        bh[pp][0] = *reinterpret_cast<const half8*>(p);
        bh[pp][1] = *reinterpret_cast<const half8*>(p + 1024);
        bl[pp][0] = *reinterpret_cast<const half8*>(p + 16384);
        bl[pp][1] = *reinterpret_cast<const half8*>(p + 16384 + 1024);
    };
    auto LDA = [&](int pp, unsigned bufc, int kk) {
        const unsigned base = bufc + (unsigned)(kk << 12) + (unsigned)(lg << 8) +
                              (unsigned)((((l15 ^ ((kk << 2) + lg)) & 15) << 4));
        axh[pp][0] = *reinterpret_cast<const half8*>(&lds[base]);
        axh[pp][1] = *reinterpret_cast<const half8*>(&lds[base + 1024]);
        axm[pp][0] = *reinterpret_cast<const half8*>(&lds[base + 2048]);
        axm[pp][1] = *reinterpret_cast<const half8*>(&lds[base + 3072]);
    };
    // convert 8 staged floats -> 2 limb vectors, write into buffer at base
    auto WRITESTEP = [&](unsigned base, const float4& a, const float4& b) {
        float v[8];
        *reinterpret_cast<float4*>(v)     = a;
        *reinterpret_cast<float4*>(v + 4) = b;
        half8 h0, h1;
#pragma unroll
        for (int j = 0; j < 8; ++j) {
            const _Float16 hh = (_Float16)v[j];
            h0[j] = hh;
            h1[j] = (_Float16)((v[j] - (float)hh) * kS);
        }
        *reinterpret_cast<half8*>(&lds[base + waddr])        = h0;
        *reinterpret_cast<half8*>(&lds[base + waddr + 2048]) = h1;
    };

    // ---- prologue: stage step 0 into buf0; B of first rotated tile -> parity 0
    {
        float4 a = *reinterpret_cast<const float4*>(xsrc);
        float4 b = *reinterpret_cast<const float4*>(xsrc + 4);
        LOADB(0, kk0);
        WRITESTEP(0, a, b);
    }
    convoy_barrier();

    for (int s = 0; s < NSTEP; ++s) {
        const unsigned bufc = (unsigned)((s & 1) << 14);
        const unsigned bufn = (unsigned)(((s + 1) & 1) << 14);
        const bool pre = (s + 1 < NSTEP);

        LDA(0, bufc, kk0);               // first rotated sub-tile A-frags
        float4 nv0{0,0,0,0}, nv1{0,0,0,0};
        if (pre) {                       // x prefetch for next step (HBM, used at step end)
            const float* p = xsrc + (s + 1) * KSTEP;
            nv0 = *reinterpret_cast<const float4*>(p);
            nv1 = *reinterpret_cast<const float4*>(p + 4);
        }

#pragma unroll
        for (int n = 0; n < 4; ++n) {
            const int kk = (kk0 + n) & 3;                // rotated sub-tile
            const int pp = n & 1;
            // next-sub-tile loads in flight across this cluster
            const int kt_next = (n < 3) ? (s * 4 + ((kk0 + n + 1) & 3))
                                        : ((s + 1) * 4 + kk0);
            if (kt_next < NT) LOADB(pp ^ 1, kt_next);
            if (n < 3)        LDA(pp ^ 1, bufc, (kk0 + n + 1) & 3);
            // ---- 12-MFMA cluster (all operands loaded one sub-tile ago)
#pragma unroll
            for (int i = 0; i < 2; ++i)
#pragma unroll
                for (int j = 0; j < 2; ++j)
                    acc0[i][j] = __builtin_amdgcn_mfma_f32_16x16x32_f16(axh[pp][i], bh[pp][j], acc0[i][j], 0, 0, 0);
#pragma unroll
            for (int i = 0; i < 2; ++i)
#pragma unroll
                for (int j = 0; j < 2; ++j)
                    acc1[i][j] = __builtin_amdgcn_mfma_f32_16x16x32_f16(axm[pp][i], bh[pp][j], acc1[i][j], 0, 0, 0);
#pragma unroll
            for (int i = 0; i < 2; ++i)
#pragma unroll
                for (int j = 0; j < 2; ++j)
                    acc1[i][j] = __builtin_amdgcn_mfma_f32_16x16x32_f16(axh[pp][i], bl[pp][j], acc1[i][j], 0, 0, 0);
        }

        if (pre) WRITESTEP(bufn, nv0, nv1);

        if (((s + 1) & 7) == 0) {        // two-level spill of acc0 every 8 steps
#pragma unroll
            for (int i = 0; i < 2; ++i)
#pragma unroll
                for (int j = 0; j < 2; ++j) {
                    accL[i][j] += acc0[i][j];
                    acc0[i][j] = f32x4{0.f,0.f,0.f,0.f};
                }
        }
        convoy_barrier();                // lgkm-only drain: B/x loads stay in flight
    }

    // ---- epilogue: combine limb levels, biased scores -> LDS
    float (*sc)[257] = reinterpret_cast<float (*)[257]>(lds);   // 32896 B, aliases A bufs
#pragma unroll
    for (int j = 0; j < 2; ++j) {
        const int col  = wid * 32 + j * 16 + l15;
        const float bv = bias[col];
#pragma unroll
        for (int i = 0; i < 2; ++i) {
            f32x4 z = (accL[i][j] + acc0[i][j]) + kC * acc1[i][j];
#pragma unroll
            for (int r = 0; r < 4; ++r) {
                const int row = i * 16 + lg * 4 + r;
                const float s = 1.0f / (1.0f + expf(-z[r]));
                sc[row][col] = s + bv;
            }
        }
    }
    __syncthreads();

    // ---- top-8 per row: 16 lanes/row (one 16-group of a wave -> wave-ordered
    // LDS, no barriers between rounds), ties -> lowest index
    const int rr = t >> 4;
    const int g  = t & 15;

    float cval[kTopK];
    int   cidx[kTopK];

#pragma unroll
    for (int r = 0; r < kTopK; ++r) {
        float best = -INFINITY;
        int   bi   = kE;
        const float* rowp = sc[rr] + g * 16;
#pragma unroll 8
        for (int c = 0; c < 16; ++c) {
            const float v  = rowp[c];
            const int   ci = g * 16 + c;
            if (v > best || (v == best && ci < bi)) { best = v; bi = ci; }
        }
#pragma unroll
        for (int off = 8; off > 0; off >>= 1) {
            const float ov = __shfl_xor(best, off, 16);
            const int   oi = __shfl_xor(bi,   off, 16);
            if (ov > best || (ov == best && oi < bi)) { best = ov; bi = oi; }
        }
        cval[r] = best;
        cidx[r] = bi;
        if ((bi >> 4) == g) sc[rr][bi] = -INFINITY;   // owner lane retires winner
    }

    if (g == 0) {
        float uw[kTopK];
        float wsum = 0.0f;
#pragma unroll
        for (int r = 0; r < kTopK; ++r) {
            uw[r] = cval[r] - bias[cidx[r]];   // recover unbiased sigmoid score
            wsum += uw[r];
        }
        const float scale = kRouteScale / wsum;
        const size_t grow = (size_t)(m0 + rr);
#pragma unroll
        for (int r = 0; r < kTopK; ++r)
            out[grow * kTopK + r] = uw[r] * scale;
#pragma unroll
        for (int r = 0; r < kTopK; ++r)
            out[(size_t)kTokens * kTopK + grow * kTopK + r] = (float)cidx[r];
    }
}

// ---------------------------------------------------------------------------
// Fallback (round-1 fp32 kernel, known-good) if ws is too small.
// ---------------------------------------------------------------------------
constexpr int FBM = 32;
constexpr int FBK = 32;
constexpr int XS_STRIDE = 36;
constexpr int SC_STRIDE = 260;

__global__ __launch_bounds__(256, 2)
void gate_fused(const float* __restrict__ x,
                const float* __restrict__ W,
                const float* __restrict__ bias,
                float* __restrict__ out)
{
    __shared__ float smem[FBK * XS_STRIDE + FBK * kE];
    float (*xs)[XS_STRIDE] = reinterpret_cast<float (*)[XS_STRIDE]>(smem);
    float (*ws)[kE]        = reinterpret_cast<float (*)[kE]>(smem + FBK * XS_STRIDE);
    float (*sc)[SC_STRIDE] = reinterpret_cast<float (*)[SC_STRIDE]>(smem);

    const int t  = threadIdx.x;
    const int tx = t & 31;
    const int ty = t >> 5;
    const int m0 = blockIdx.x * FBM;
    const int lm = t >> 3;
    const int lc = t & 7;

    float acc[4][8];
    float cmp[4][8];
#pragma unroll
    for (int i = 0; i < 4; ++i)
#pragma unroll
        for (int j = 0; j < 8; ++j) { acc[i][j] = 0.0f; cmp[i][j] = 0.0f; }

    const float* xrow = x + (size_t)(m0 + lm) * kD;
    const float* wrow = W + (size_t)t * kD;

    for (int k0 = 0; k0 < kD; k0 += FBK) {
        float4 xv = *reinterpret_cast<const float4*>(xrow + k0 + 4 * lc);
        float4 wv[8];
#pragma unroll
        for (int i = 0; i < 8; ++i)
            wv[i] = *reinterpret_cast<const float4*>(wrow + k0 + 4 * i);
        __syncthreads();
        xs[4 * lc + 0][lm] = xv.x; xs[4 * lc + 1][lm] = xv.y;
        xs[4 * lc + 2][lm] = xv.z; xs[4 * lc + 3][lm] = xv.w;
#pragma unroll
        for (int i = 0; i < 8; ++i) {
            ws[4 * i + 0][t] = wv[i].x; ws[4 * i + 1][t] = wv[i].y;
            ws[4 * i + 2][t] = wv[i].z; ws[4 * i + 3][t] = wv[i].w;
        }
        __syncthreads();
        float p[4][8];
#pragma unroll
        for (int i = 0; i < 4; ++i)
#pragma unroll
            for (int j = 0; j < 8; ++j) p[i][j] = 0.0f;
#pragma unroll
        for (int k = 0; k < FBK; ++k) {
            float a[4], b[8];
            *reinterpret_cast<float4*>(a)     = *reinterpret_cast<const float4*>(&xs[k][4 * ty]);
            *reinterpret_cast<float4*>(b)     = *reinterpret_cast<const float4*>(&ws[k][4 * tx]);
            *reinterpret_cast<float4*>(b + 4) = *reinterpret_cast<const float4*>(&ws[k][128 + 4 * tx]);
#pragma unroll
            for (int i = 0; i < 4; ++i)
#pragma unroll
                for (int j = 0; j < 8; ++j)
                    p[i][j] = fmaf(a[i], b[j], p[i][j]);
        }
#pragma unroll
        for (int i = 0; i < 4; ++i)
#pragma unroll
            for (int j = 0; j < 8; ++j) {
                const float y = p[i][j] - cmp[i][j];
                const float s = acc[i][j] + y;
                cmp[i][j] = (s - acc[i][j]) - y;
                acc[i][j] = s;
            }
    }
    __syncthreads();
#pragma unroll
    for (int i = 0; i < 4; ++i) {
        const int row = 4 * ty + i;
#pragma unroll
        for (int j = 0; j < 8; ++j) {
            const int col = (j < 4) ? (4 * tx + j) : (128 + 4 * tx + (j - 4));
            const float s = 1.0f / (1.0f + expf(-acc[i][j]));
            sc[row][col] = s + bias[col];
        }
    }
    __syncthreads();
    const int rr = t >> 3;
    const int g  = t & 7;
    float cval[kTopK];
    int   cidx[kTopK];
#pragma unroll
    for (int r = 0; r < kTopK; ++r) {
        float best = -INFINITY;
        int   bi   = kE;
        const float* rowp = sc[rr] + g * 32;
#pragma unroll 8
        for (int c = 0; c < 32; ++c) {
            const float v  = rowp[c];
            const int   ci = g * 32 + c;
            if (v > best || (v == best && ci < bi)) { best = v; bi = ci; }
        }
#pragma unroll
        for (int off = 4; off > 0; off >>= 1) {
            const float ov = __shfl_xor(best, off, 8);
            const int   oi = __shfl_xor(bi,   off, 8);
            if (ov > best || (ov == best && oi < bi)) { best = ov; bi = oi; }
        }
        cval[r] = best; cidx[r] = bi;
        if ((bi >> 5) == g) sc[rr][bi] = -INFINITY;
        __syncthreads();
    }
    if (g == 0) {
        float uw[kTopK];
        float wsum = 0.0f;
#pragma unroll
        for (int r = 0; r < kTopK; ++r) { uw[r] = cval[r] - bias[cidx[r]]; wsum += uw[r]; }
        const float scale = kRouteScale / wsum;
        const size_t grow = (size_t)(m0 + rr);
#pragma unroll
        for (int r = 0; r < kTopK; ++r) out[grow * kTopK + r] = uw[r] * scale;
#pragma unroll
        for (int r = 0; r < kTopK; ++r)
            out[(size_t)kTokens * kTopK + grow * kTopK + r] = (float)cidx[r];
    }
}

} // namespace

extern "C" void kernel_launch(void* const* d_in, const int* in_sizes, int n_in,
                              void* d_out, int out_size, void* d_ws, size_t ws_size,
                              hipStream_t stream)
{
    const float* x    = (const float*)d_in[0];
    const float* W    = (const float*)d_in[1];
    const float* bias = (const float*)d_in[2];
    float* out = (float*)d_out;

    if (ws_size >= kWsNeed) {
        unsigned char* ws = (unsigned char*)d_ws;
        hipLaunchKernelGGL(wconv_kernel, dim3(kE), dim3(kD / 8), 0, stream, W, ws);
        hipLaunchKernelGGL(gate_mfma, dim3(kTokens / BM), dim3(512), 0, stream, x, ws, bias, out);
    } else {
        hipLaunchKernelGGL(gate_fused, dim3(kTokens / FBM), dim3(256), 0, stream, x, W, bias, out);
    }
}

// Round 13
// 242.922 us; speedup vs baseline: 1.1469x; 1.1469x over previous
//
#include <hip/hip_runtime.h>
#include <cmath>

namespace {

typedef _Float16 half8 __attribute__((ext_vector_type(8)));
typedef float f32x4 __attribute__((ext_vector_type(4)));

constexpr int kTokens = 16384;
constexpr int kD      = 7168;
constexpr int kE      = 256;
constexpr int kTopK   = 8;
constexpr float kRouteScale = 2.5f;

constexpr int BM     = 64;
constexpr int BK     = 32;               // MFMA k-tile
constexpr int KSTEP  = 64;               // k per barrier step (2 tiles)
constexpr int NT     = kD / BK;          // 224 k-tiles
constexpr int NSTEP  = kD / KSTEP;       // 112 steps
constexpr float kS  = 4096.0f;           // limb scale 2^12
constexpr float kC  = 0.000244140625f;   // 2^-12 (exact)
constexpr size_t kWsTileB = 32768;       // per-ktile W image: limb0 16K + limb1 16K
constexpr size_t kWsNeed  = (size_t)NT * kWsTileB;   // 7,340,032 B

// Convoy barrier WITHOUT the __syncthreads vmcnt(0) drain: only LDS ops must
// retire for cross-wave visibility (vmem results are per-lane registers).
__device__ inline void convoy_barrier() {
    asm volatile("s_waitcnt lgkmcnt(0)" ::: "memory");
    __builtin_amdgcn_s_barrier();
    asm volatile("" ::: "memory");
}

// ---------------------------------------------------------------------------
// Pre-pass: W [256][7168] f32 -> per-ktile B-fragment images, 2 scaled f16
// limbs.  Slot for expert e, k-group kg (8 k's): (e>>4)*64 + kg*16 + (e&15).
// Lane l of a wave reading colfrag f at f*1024 + l*16 gets its MFMA B frag.
// (unchanged since r3; validated absmax 0)
// ---------------------------------------------------------------------------
__global__ void wconv_kernel(const float* __restrict__ W, unsigned char* __restrict__ ws)
{
    const int e = blockIdx.x;
    const int t = threadIdx.x;            // 0..895
    const float* src = W + (size_t)e * kD + (size_t)t * 8;
    float v[8];
    *reinterpret_cast<float4*>(v)     = *reinterpret_cast<const float4*>(src);
    *reinterpret_cast<float4*>(v + 4) = *reinterpret_cast<const float4*>(src + 4);
    half8 h, l;
#pragma unroll
    for (int j = 0; j < 8; ++j) {
        _Float16 hh = (_Float16)v[j];
        h[j] = hh;
        l[j] = (_Float16)((v[j] - (float)hh) * kS);
    }
    const int kt = t >> 2;
    const int kg = t & 3;
    const size_t off = (size_t)kt * kWsTileB +
                       (size_t)(((e >> 4) << 6) + (kg << 4) + (e & 15)) * 16;
    *reinterpret_cast<half8*>(ws + off)         = h;
    *reinterpret_cast<half8*>(ws + off + 16384) = l;
}

// ---------------------------------------------------------------------------
// Main fused kernel, round 13: BYTE-VOLUME attack (r7-r12 showed the convoy
// is bytes-bound, not scheduling-bound).
//   * BM=64, grid 256 = 1 block/CU: B read ONCE per CU per k-tile (each of
//     the 16 colfrags owned by exactly one wave) -> VMEM-B per CU halved.
//   * 8 waves, wave tile 64x32 (4 rowfrags x 2 colfrags): LDS-A bytes per CU
//     halved (one block stages/reads instead of two); VALU conversion halved.
//   * KSTEP=64, A dbuf 2x16KB, r7-proven staging map (8 k's of one row per
//     thread) + XOR slot swizzle -> conflict-free writes and reads.
//   * B: direct global->reg ping-pong, STATIC parity p=kk (2 kt/step).
//   * Numerics (validated r7/r10): 3 products, acc0 -> accL spill every 16
//     steps (= 32 k-tiles, same cadence as r7).
// LDS: A bufs 2x16KB at [0,32768), aliased by epilogue sc[64][257] (65792 B).
// ---------------------------------------------------------------------------
__global__ __launch_bounds__(512, 2)
void gate_mfma(const float* __restrict__ x,
               const unsigned char* __restrict__ wst,
               const float* __restrict__ bias,
               float* __restrict__ out)
{
    __shared__ unsigned char lds[65792];

    const int t    = threadIdx.x;
    const int lane = t & 63;
    const int wid  = t >> 6;             // 0..7 -> 32-col group (2 colfrags)
    const int m0   = blockIdx.x * BM;
    const int l15  = lane & 15;
    const int lg   = lane >> 4;

    // --- A staging map: thread t stages 8 consecutive k's of one row.
    // srow 0..63, skc 0..7 (k = skc*8..+7 within the 64-k step).
    // buffer layout: kk*8192 + limb*4096 + rf*1024 + kq*256 + slot*16,
    // slot = (srow&15) ^ skc  (bijective per (kk,kq,rf); <=2-way banks)
    const int srow = t >> 3;             // 0..63
    const int skc  = t & 7;              // kk = skc>>2, kq = skc&3
    const unsigned waddr = (unsigned)(((skc >> 2) << 13) + ((srow >> 4) << 10) +
                                      ((skc & 3) << 8) + (((srow & 15) ^ skc) << 4));
    const float* xsrc = x + (size_t)(m0 + srow) * kD + (size_t)(skc * 8);

    // --- B: lane's fragment pointer (colfrags wid*2, wid*2+1)
    const unsigned char* wb = wst + (size_t)(wid * 2) * 1024 + (size_t)lane * 16;

    f32x4 acc0[4][2], acc1[4][2], accL[4][2];
#pragma unroll
    for (int i = 0; i < 4; ++i)
#pragma unroll
        for (int j = 0; j < 2; ++j) {
            acc0[i][j] = f32x4{0.f,0.f,0.f,0.f};
            acc1[i][j] = f32x4{0.f,0.f,0.f,0.f};
            accL[i][j] = f32x4{0.f,0.f,0.f,0.f};
        }

    half8 bh[2][2];      // [parity kk][colfrag]  W limb0
    half8 bl[2][2];      // [parity kk][colfrag]  W limb1
    half8 axh[2][4];     // [parity kk][rowfrag]  A limb0
    half8 axm[2][4];     // [parity kk][rowfrag]  A limb1

    auto LOADB = [&](int pp, int kt) {
        const unsigned char* p = wb + (size_t)kt * kWsTileB;
        bh[pp][0] = *reinterpret_cast<const half8*>(p);
        bh[pp][1] = *reinterpret_cast<const half8*>(p + 1024);
        bl[pp][0] = *reinterpret_cast<const half8*>(p + 16384);
        bl[pp][1] = *reinterpret_cast<const half8*>(p + 16384 + 1024);
    };
    auto LDA = [&](int pp, unsigned bufc, int kk) {
        const unsigned base = bufc + (unsigned)(kk << 13) + (unsigned)(lg << 8) +
                              (unsigned)((((l15 ^ ((kk << 2) + lg)) & 15) << 4));
#pragma unroll
        for (int i = 0; i < 4; ++i) {
            axh[pp][i] = *reinterpret_cast<const half8*>(&lds[base + i * 1024]);
            axm[pp][i] = *reinterpret_cast<const half8*>(&lds[base + i * 1024 + 4096]);
        }
    };
    // convert 8 staged floats -> 2 limb vectors, write into buffer at base
    auto WRITESTEP = [&](unsigned base, const float4& a, const float4& b) {
        float v[8];
        *reinterpret_cast<float4*>(v)     = a;
        *reinterpret_cast<float4*>(v + 4) = b;
        half8 h0, h1;
#pragma unroll
        for (int j = 0; j < 8; ++j) {
            const _Float16 hh = (_Float16)v[j];
            h0[j] = hh;
            h1[j] = (_Float16)((v[j] - (float)hh) * kS);
        }
        *reinterpret_cast<half8*>(&lds[base + waddr])        = h0;
        *reinterpret_cast<half8*>(&lds[base + waddr + 4096]) = h1;
    };

    // ---- prologue: stage step 0 into buf0; B k-tile 0 into parity 0
    {
        float4 a = *reinterpret_cast<const float4*>(xsrc);
        float4 b = *reinterpret_cast<const float4*>(xsrc + 4);
        LOADB(0, 0);
        WRITESTEP(0, a, b);
    }
    convoy_barrier();

    for (int s = 0; s < NSTEP; ++s) {
        const unsigned bufc = (unsigned)((s & 1) << 14);
        const unsigned bufn = (unsigned)(((s + 1) & 1) << 14);
        const bool pre = (s + 1 < NSTEP);

        LDA(0, bufc, 0);                 // k-tile 0 A-frags (8 ds_read_b128)
        float4 nv0{0,0,0,0}, nv1{0,0,0,0};
        if (pre) {                       // x prefetch for next step
            const float* p = xsrc + (s + 1) * KSTEP;
            nv0 = *reinterpret_cast<const float4*>(p);
            nv1 = *reinterpret_cast<const float4*>(p + 4);
        }

#pragma unroll
        for (int kk = 0; kk < 2; ++kk) { // static parity p = kk
            const int kt_next = s * 2 + kk + 1;
            if (kt_next < NT) LOADB(kk ^ 1, kt_next);  // next B in flight
            if (kk == 0)      LDA(1, bufc, 1);         // next A frags in flight
            // ---- 24-MFMA cluster
#pragma unroll
            for (int i = 0; i < 4; ++i)
#pragma unroll
                for (int j = 0; j < 2; ++j)
                    acc0[i][j] = __builtin_amdgcn_mfma_f32_16x16x32_f16(axh[kk][i], bh[kk][j], acc0[i][j], 0, 0, 0);
#pragma unroll
            for (int i = 0; i < 4; ++i)
#pragma unroll
                for (int j = 0; j < 2; ++j)
                    acc1[i][j] = __builtin_amdgcn_mfma_f32_16x16x32_f16(axm[kk][i], bh[kk][j], acc1[i][j], 0, 0, 0);
#pragma unroll
            for (int i = 0; i < 4; ++i)
#pragma unroll
                for (int j = 0; j < 2; ++j)
                    acc1[i][j] = __builtin_amdgcn_mfma_f32_16x16x32_f16(axh[kk][i], bl[kk][j], acc1[i][j], 0, 0, 0);
        }

        if (pre) WRITESTEP(bufn, nv0, nv1);

        if (((s + 1) & 15) == 0) {       // acc0 spill every 32 k-tiles (r7 cadence)
#pragma unroll
            for (int i = 0; i < 4; ++i)
#pragma unroll
                for (int j = 0; j < 2; ++j) {
                    accL[i][j] += acc0[i][j];
                    acc0[i][j] = f32x4{0.f,0.f,0.f,0.f};
                }
        }
        convoy_barrier();                // lgkm-only drain: B/x loads stay in flight
    }

    // ---- epilogue: combine limb levels, biased scores -> LDS
    float (*sc)[257] = reinterpret_cast<float (*)[257]>(lds);   // 65792 B, aliases A bufs
#pragma unroll
    for (int j = 0; j < 2; ++j) {
        const int col  = wid * 32 + j * 16 + l15;
        const float bv = bias[col];
#pragma unroll
        for (int i = 0; i < 4; ++i) {
            f32x4 z = (accL[i][j] + acc0[i][j]) + kC * acc1[i][j];
#pragma unroll
            for (int r = 0; r < 4; ++r) {
                const int row = i * 16 + lg * 4 + r;
                const float s = 1.0f / (1.0f + expf(-z[r]));
                sc[row][col] = s + bv;
            }
        }
    }
    __syncthreads();

    // ---- top-8 per row: 8 lanes/row (same wave -> wave-ordered LDS, no
    // barriers between rounds), iterative argmax, ties -> lowest index
    const int rr = t >> 3;               // 0..63
    const int g  = t & 7;

    float cval[kTopK];
    int   cidx[kTopK];

#pragma unroll
    for (int r = 0; r < kTopK; ++r) {
        float best = -INFINITY;
        int   bi   = kE;
        const float* rowp = sc[rr] + g * 32;
#pragma unroll 8
        for (int c = 0; c < 32; ++c) {
            const float v  = rowp[c];
            const int   ci = g * 32 + c;
            if (v > best || (v == best && ci < bi)) { best = v; bi = ci; }
        }
#pragma unroll
        for (int off = 4; off > 0; off >>= 1) {
            const float ov = __shfl_xor(best, off, 8);
            const int   oi = __shfl_xor(bi,   off, 8);
            if (ov > best || (ov == best && oi < bi)) { best = ov; bi = oi; }
        }
        cval[r] = best;
        cidx[r] = bi;
        if ((bi >> 5) == g) sc[rr][bi] = -INFINITY;   // owner lane retires winner
    }

    if (g == 0) {
        float uw[kTopK];
        float wsum = 0.0f;
#pragma unroll
        for (int r = 0; r < kTopK; ++r) {
            uw[r] = cval[r] - bias[cidx[r]];   // recover unbiased sigmoid score
            wsum += uw[r];
        }
        const float scale = kRouteScale / wsum;
        const size_t grow = (size_t)(m0 + rr);
#pragma unroll
        for (int r = 0; r < kTopK; ++r)
            out[grow * kTopK + r] = uw[r] * scale;
#pragma unroll
        for (int r = 0; r < kTopK; ++r)
            out[(size_t)kTokens * kTopK + grow * kTopK + r] = (float)cidx[r];
    }
}

// ---------------------------------------------------------------------------
// Fallback (round-1 fp32 kernel, known-good) if ws is too small.
// ---------------------------------------------------------------------------
constexpr int FBM = 32;
constexpr int FBK = 32;
constexpr int XS_STRIDE = 36;
constexpr int SC_STRIDE = 260;

__global__ __launch_bounds__(256, 2)
void gate_fused(const float* __restrict__ x,
                const float* __restrict__ W,
                const float* __restrict__ bias,
                float* __restrict__ out)
{
    __shared__ float smem[FBK * XS_STRIDE + FBK * kE];
    float (*xs)[XS_STRIDE] = reinterpret_cast<float (*)[XS_STRIDE]>(smem);
    float (*ws)[kE]        = reinterpret_cast<float (*)[kE]>(smem + FBK * XS_STRIDE);
    float (*sc)[SC_STRIDE] = reinterpret_cast<float (*)[SC_STRIDE]>(smem);

    const int t  = threadIdx.x;
    const int tx = t & 31;
    const int ty = t >> 5;
    const int m0 = blockIdx.x * FBM;
    const int lm = t >> 3;
    const int lc = t & 7;

    float acc[4][8];
    float cmp[4][8];
#pragma unroll
    for (int i = 0; i < 4; ++i)
#pragma unroll
        for (int j = 0; j < 8; ++j) { acc[i][j] = 0.0f; cmp[i][j] = 0.0f; }

    const float* xrow = x + (size_t)(m0 + lm) * kD;
    const float* wrow = W + (size_t)t * kD;

    for (int k0 = 0; k0 < kD; k0 += FBK) {
        float4 xv = *reinterpret_cast<const float4*>(xrow + k0 + 4 * lc);
        float4 wv[8];
#pragma unroll
        for (int i = 0; i < 8; ++i)
            wv[i] = *reinterpret_cast<const float4*>(wrow + k0 + 4 * i);
        __syncthreads();
        xs[4 * lc + 0][lm] = xv.x; xs[4 * lc + 1][lm] = xv.y;
        xs[4 * lc + 2][lm] = xv.z; xs[4 * lc + 3][lm] = xv.w;
#pragma unroll
        for (int i = 0; i < 8; ++i) {
            ws[4 * i + 0][t] = wv[i].x; ws[4 * i + 1][t] = wv[i].y;
            ws[4 * i + 2][t] = wv[i].z; ws[4 * i + 3][t] = wv[i].w;
        }
        __syncthreads();
        float p[4][8];
#pragma unroll
        for (int i = 0; i < 4; ++i)
#pragma unroll
            for (int j = 0; j < 8; ++j) p[i][j] = 0.0f;
#pragma unroll
        for (int k = 0; k < FBK; ++k) {
            float a[4], b[8];
            *reinterpret_cast<float4*>(a)     = *reinterpret_cast<const float4*>(&xs[k][4 * ty]);
            *reinterpret_cast<float4*>(b)     = *reinterpret_cast<const float4*>(&ws[k][4 * tx]);
            *reinterpret_cast<float4*>(b + 4) = *reinterpret_cast<const float4*>(&ws[k][128 + 4 * tx]);
#pragma unroll
            for (int i = 0; i < 4; ++i)
#pragma unroll
                for (int j = 0; j < 8; ++j)
                    p[i][j] = fmaf(a[i], b[j], p[i][j]);
        }
#pragma unroll
        for (int i = 0; i < 4; ++i)
#pragma unroll
            for (int j = 0; j < 8; ++j) {
                const float y = p[i][j] - cmp[i][j];
                const float s = acc[i][j] + y;
                cmp[i][j] = (s - acc[i][j]) - y;
                acc[i][j] = s;
            }
    }
    __syncthreads();
#pragma unroll
    for (int i = 0; i < 4; ++i) {
        const int row = 4 * ty + i;
#pragma unroll
        for (int j = 0; j < 8; ++j) {
            const int col = (j < 4) ? (4 * tx + j) : (128 + 4 * tx + (j - 4));
            const float s = 1.0f / (1.0f + expf(-acc[i][j]));
            sc[row][col] = s + bias[col];
        }
    }
    __syncthreads();
    const int rr = t >> 3;
    const int g  = t & 7;
    float cval[kTopK];
    int   cidx[kTopK];
#pragma unroll
    for (int r = 0; r < kTopK; ++r) {
        float best = -INFINITY;
        int   bi   = kE;
        const float* rowp = sc[rr] + g * 32;
#pragma unroll 8
        for (int c = 0; c < 32; ++c) {
            const float v  = rowp[c];
            const int   ci = g * 32 + c;
            if (v > best || (v == best && ci < bi)) { best = v; bi = ci; }
        }
#pragma unroll
        for (int off = 4; off > 0; off >>= 1) {
            const float ov = __shfl_xor(best, off, 8);
            const int   oi = __shfl_xor(bi,   off, 8);
            if (ov > best || (ov == best && oi < bi)) { best = ov; bi = oi; }
        }
        cval[r] = best; cidx[r] = bi;
        if ((bi >> 5) == g) sc[rr][bi] = -INFINITY;
        __syncthreads();
    }
    if (g == 0) {
        float uw[kTopK];
        float wsum = 0.0f;
#pragma unroll
        for (int r = 0; r < kTopK; ++r) { uw[r] = cval[r] - bias[cidx[r]]; wsum += uw[r]; }
        const float scale = kRouteScale / wsum;
        const size_t grow = (size_t)(m0 + rr);
#pragma unroll
        for (int r = 0; r < kTopK; ++r) out[grow * kTopK + r] = uw[r] * scale;
#pragma unroll
        for (int r = 0; r < kTopK; ++r)
            out[(size_t)kTokens * kTopK + grow * kTopK + r] = (float)cidx[r];
    }
}

} // namespace

extern "C" void kernel_launch(void* const* d_in, const int* in_sizes, int n_in,
                              void* d_out, int out_size, void* d_ws, size_t ws_size,
                              hipStream_t stream)
{
    const float* x    = (const float*)d_in[0];
    const float* W    = (const float*)d_in[1];
    const float* bias = (const float*)d_in[2];
    float* out = (float*)d_out;

    if (ws_size >= kWsNeed) {
        unsigned char* ws = (unsigned char*)d_ws;
        hipLaunchKernelGGL(wconv_kernel, dim3(kE), dim3(kD / 8), 0, stream, W, ws);
        hipLaunchKernelGGL(gate_mfma, dim3(kTokens / BM), dim3(512), 0, stream, x, ws, bias, out);
    } else {
        hipLaunchKernelGGL(gate_fused, dim3(kTokens / FBM), dim3(256), 0, stream, x, W, bias, out);
    }
}